// Round 1
// 713.309 us; speedup vs baseline: 1.0119x; 1.0119x over previous
//
#include <hip/hip_runtime.h>
#include <hip/hip_bf16.h>

#define NN 8192
#define RW 10
#define H1 100
#define H2 100
#define NB 256

constexpr int CHUNK   = 1024;          // m-values per K-chunk (40 KB LDS)
constexpr int NCHUNKS = NN / CHUNK;    // 8
constexpr int SUB     = CHUNK / 256;   // 4 sub-iterations / staging rows per thread

// Kernel A: hopX[k][n][d] = sum_m hop_k[n][m] * X[m][d]
// 4 waves/block, one row per wave. X chunk staged d-major in LDS.
// CHUNK=1024: only 2 barriers per 1024 m (8 barrier-drains per row instead of
// 64), and all 12 hop float4 loads of a chunk are issued before the FMA block
// so they stay in flight together (the old version had only 3 loads in flight
// between vmcnt(0) barrier drains -> latency-bound at 1.9 TB/s HBM).
__global__ __launch_bounds__(256) void hopx_kernel(
    const float* __restrict__ X,
    const float* __restrict__ hop1,
    const float* __restrict__ hop2,
    const float* __restrict__ hop3,
    float* __restrict__ hopX)
{
    __shared__ float Xs[RW][CHUNK];   // 40 KB, d-major -> 4 blocks/CU (LDS-limited)

    const int tid  = threadIdx.x;
    const int wave = tid >> 6;
    const int lane = tid & 63;
    const int n    = blockIdx.x * 4 + wave;

    float acc[3][RW];
    #pragma unroll
    for (int k = 0; k < 3; ++k)
        #pragma unroll
        for (int d = 0; d < RW; ++d) acc[k][d] = 0.f;

    const float* __restrict__ r1 = hop1 + (size_t)n * NN;
    const float* __restrict__ r2 = hop2 + (size_t)n * NN;
    const float* __restrict__ r3 = hop3 + (size_t)n * NN;

    for (int c = 0; c < NCHUNKS; ++c) {
        const int m0 = c * CHUNK;

        // stage X[m0 .. m0+1023][0..9] into d-major LDS; thread t stages rows
        // m0+t+256*s (40 B contiguous per row, consecutive threads contiguous
        // -> coalesced float2 segments; LDS writes lane-consecutive -> no
        // bank conflicts)
        #pragma unroll
        for (int s = 0; s < SUB; ++s) {
            const int m = tid + 256 * s;
            const float2* src = (const float2*)(X + (size_t)(m0 + m) * RW);
            float2 v0 = src[0], v1 = src[1], v2 = src[2], v3 = src[3], v4 = src[4];
            Xs[0][m] = v0.x; Xs[1][m] = v0.y;
            Xs[2][m] = v1.x; Xs[3][m] = v1.y;
            Xs[4][m] = v2.x; Xs[5][m] = v2.y;
            Xs[6][m] = v3.x; Xs[7][m] = v3.y;
            Xs[8][m] = v4.x; Xs[9][m] = v4.y;
        }
        __syncthreads();

        // issue ALL hop loads for this chunk first (12 float4 in flight/lane),
        // statically indexed arrays so they stay in registers (no scratch)
        float4 h0[SUB], h1[SUB], h2[SUB];
        #pragma unroll
        for (int s = 0; s < SUB; ++s) {
            const int mi = m0 + 256 * s + 4 * lane;
            h0[s] = *(const float4*)(r1 + mi);
            h1[s] = *(const float4*)(r2 + mi);
            h2[s] = *(const float4*)(r3 + mi);
        }

        #pragma unroll
        for (int s = 0; s < SUB; ++s) {
            #pragma unroll
            for (int d = 0; d < RW; ++d) {
                float4 xv = *(const float4*)&Xs[d][4 * lane + 256 * s]; // ds_read_b128
                acc[0][d] += h0[s].x * xv.x; acc[0][d] += h0[s].y * xv.y;
                acc[0][d] += h0[s].z * xv.z; acc[0][d] += h0[s].w * xv.w;
                acc[1][d] += h1[s].x * xv.x; acc[1][d] += h1[s].y * xv.y;
                acc[1][d] += h1[s].z * xv.z; acc[1][d] += h1[s].w * xv.w;
                acc[2][d] += h2[s].x * xv.x; acc[2][d] += h2[s].y * xv.y;
                acc[2][d] += h2[s].z * xv.z; acc[2][d] += h2[s].w * xv.w;
            }
        }
        __syncthreads();
    }

    // wave-wide reduction (64 lanes), lane 0 writes 30 results for this row
    #pragma unroll
    for (int k = 0; k < 3; ++k) {
        #pragma unroll
        for (int d = 0; d < RW; ++d) {
            float v = acc[k][d];
            #pragma unroll
            for (int off = 32; off > 0; off >>= 1)
                v += __shfl_down(v, off, 64);
            if (lane == 0)
                hopX[((size_t)k * NN + n) * RW + d] = v;
        }
    }
}

// Kernel B: one block per batch segment b.
// h[k][n] = relu(inp[k][n] @ W1[k] + b1[k]) accumulated (segment-sum) in
// registers across the segment's nodes (thread t<400 owns (k,h)=(t/100,t%100)),
// then pooled[b] = sum_k Hacc[k] @ W2[k] + count_b * sum_k b2[k]. No atomics.
__global__ __launch_bounds__(512) void mlp_pool_kernel(
    const float* __restrict__ X,
    const float* __restrict__ hopX,
    const int*   __restrict__ batch_idx,
    const float* __restrict__ W1,
    const float* __restrict__ b1,
    const float* __restrict__ W2,
    const float* __restrict__ b2,
    float* __restrict__ out)
{
    const int b = blockIdx.x;
    const int t = threadIdx.x;

    // binary-search segment [lo, hi) in sorted batch_idx (uniform per block)
    int lo, hi;
    {
        int l = 0, r = NN;
        while (l < r) { int mid = (l + r) >> 1; if (batch_idx[mid] < b) l = mid + 1; else r = mid; }
        lo = l;
        r = NN;
        while (l < r) { int mid = (l + r) >> 1; if (batch_idx[mid] < b + 1) l = mid + 1; else r = mid; }
        hi = l;
    }

    __shared__ float inpS[8][40];   // 8 nodes x (4k x 10d)
    __shared__ float hbuf[400];

    const int k = t / 100;
    const int h = t % 100;
    float w1col[RW];
    float bias = 0.f;
    if (t < 400) {
        #pragma unroll
        for (int d = 0; d < RW; ++d)
            w1col[d] = W1[k * (RW * H1) + d * H1 + h];
        bias = b1[k * H1 + h];
    }

    float hacc = 0.f;
    for (int base = lo; base < hi; base += 8) {
        const int cnt = min(8, hi - base);
        // stage inp for up to 8 nodes: slot = kk*10+dd; kk==0 -> X else hopX
        if (t < cnt * 40) {
            const int nn   = base + t / 40;
            const int slot = t % 40;
            const int kk   = slot / 10, dd = slot % 10;
            inpS[t / 40][slot] = (kk == 0)
                ? X[(size_t)nn * RW + dd]
                : hopX[((size_t)(kk - 1) * NN + nn) * RW + dd];
        }
        __syncthreads();
        if (t < 400) {
            for (int j = 0; j < cnt; ++j) {
                float v = bias;
                #pragma unroll
                for (int d = 0; d < RW; ++d)
                    v += inpS[j][k * RW + d] * w1col[d];
                hacc += fmaxf(v, 0.f);
            }
        }
        __syncthreads();
    }

    if (t < 400) hbuf[t] = hacc;
    __syncthreads();

    if (t < H2) {
        float acc2 = 0.f;
        #pragma unroll 4
        for (int kh = 0; kh < 4 * H1; ++kh)
            acc2 += hbuf[kh] * W2[kh * H2 + t];   // hbuf broadcast, W2 coalesced
        const float bs = b2[t] + b2[H2 + t] + b2[2 * H2 + t] + b2[3 * H2 + t];
        out[b * H2 + t] = acc2 + (float)(hi - lo) * bs;
    }
}

extern "C" void kernel_launch(void* const* d_in, const int* in_sizes, int n_in,
                              void* d_out, int out_size, void* d_ws, size_t ws_size,
                              hipStream_t stream) {
    const float* walk_feats = (const float*)d_in[0];
    const float* hop1       = (const float*)d_in[1];
    const float* hop2       = (const float*)d_in[2];
    const float* hop3       = (const float*)d_in[3];
    const int*   batch_idx  = (const int*)  d_in[4];
    const float* W1         = (const float*)d_in[5];
    const float* b1         = (const float*)d_in[6];
    const float* W2         = (const float*)d_in[7];
    const float* b2         = (const float*)d_in[8];
    float* out = (float*)d_out;

    float* hopX = (float*)d_ws;   // 3 * 8192 * 10 floats = 983 KB

    hopx_kernel<<<NN / 4, 256, 0, stream>>>(walk_feats, hop1, hop2, hop3, hopX);
    mlp_pool_kernel<<<NB, 512, 0, stream>>>(walk_feats, hopX, batch_idx,
                                            W1, b1, W2, b2, out);
}